// Round 1
// baseline (280.211 us; speedup 1.0000x reference)
//
#include <hip/hip_runtime.h>

#define LSEQ 900
#define DDOP 80
#define UWIN 45
#define WHALF 22
#define BATCH 4
#define NWIN (BATCH*LSEQ)

__device__ __forceinline__ float eluf(float x){ return x > 0.f ? x : expm1f(x); }

// Generic fused conv3x3(SAME) + ELU + maxpool stage operating on zero-padded LDS tiles.
// in : [IC][IH+2][IW+2] padded;  out (PADOUT): [OC][PH+2][PW+2] padded (halo zeroed here)
//                                out (!PADOUT): [OC][PH][PW] compact
template<int IC,int OC,int IH,int IW,int PLH,int PLW,bool PADOUT>
__device__ __forceinline__ void conv_pool(const float* __restrict__ in, float* __restrict__ out,
                                          const float* __restrict__ wpad, const float* __restrict__ bias,
                                          int tid)
{
  constexpr int PH  = IH/PLH, PW = IW/PLW;
  constexpr int IHP = IH+2,  IWP = IW+2;
  constexpr int OHP = PH+2,  OWP = PW+2;
  constexpr int PRH = PLH+2, PRW = PLW+2;   // patch size per pooled output

  if (PADOUT) {
    for (int t = tid; t < OC*OHP*OWP; t += 256) {
      int rem = t % (OHP*OWP); int r = rem/OWP, c = rem%OWP;
      if (r==0 || r==OHP-1 || c==0 || c==OWP-1) out[t] = 0.f;
    }
  }
  for (int o = tid; o < OC*PH*PW; o += 256) {
    const int oc = o/(PH*PW); const int rem = o%(PH*PW);
    const int pr = rem/PW;    const int pc = rem%PW;
    float s[PLH][PLW];
    #pragma unroll
    for (int a=0;a<PLH;++a)
      #pragma unroll
      for (int bb=0;bb<PLW;++bb) s[a][bb] = bias[oc];
    for (int ic=0; ic<IC; ++ic) {
      float p[PRH][PRW];
      const float* bp = in + (ic*IHP + pr*PLH)*IWP + pc*PLW;   // even offset -> 8B aligned
      #pragma unroll
      for (int rr=0; rr<PRH; ++rr) {
        const float2* row = (const float2*)(bp + rr*IWP);
        #pragma unroll
        for (int cc=0; cc<PRW/2; ++cc) { float2 t2 = row[cc]; p[rr][2*cc]=t2.x; p[rr][2*cc+1]=t2.y; }
      }
      const float4* wv4 = (const float4*)(wpad + (oc*IC+ic)*12);  // 12-float padded 3x3 kernel
      float4 w0 = wv4[0], w1 = wv4[1], w2 = wv4[2];
      const float wr[9] = {w0.x,w0.y,w0.z,w0.w, w1.x,w1.y,w1.z,w1.w, w2.x};
      #pragma unroll
      for (int a=0;a<PLH;++a)
        #pragma unroll
        for (int bb=0;bb<PLW;++bb)
          #pragma unroll
          for (int dr=0;dr<3;++dr)
            #pragma unroll
            for (int dc=0;dc<3;++dc)
              s[a][bb] += wr[dr*3+dc]*p[a+dr][bb+dc];
    }
    float mx = s[0][0];
    #pragma unroll
    for (int a=0;a<PLH;++a)
      #pragma unroll
      for (int bb=0;bb<PLW;++bb) mx = fmaxf(mx, s[a][bb]);
    float val = eluf(mx);       // elu(max) == max(elu) (monotone)
    if (PADOUT) out[(oc*OHP + pr+1)*OWP + pc+1] = val;
    else        out[o] = val;   // oc*25 + r*5 + c == reference flatten order
  }
}

// sW layout (floats): cw1p 0..48, cw2p 48..432, cw3p 432..1968, cw4p 1968..5040,
//                     cb1 5040, cb2 5044, cb3 5052, cb4 5068  (total 5084)
__global__ __launch_bounds__(256) void encoder_kernel(
    const float* __restrict__ z, const float* __restrict__ toh,
    const float* __restrict__ cw1, const float* __restrict__ cb1,
    const float* __restrict__ cw2, const float* __restrict__ cb2,
    const float* __restrict__ cw3, const float* __restrict__ cb3,
    const float* __restrict__ cw4, const float* __restrict__ cb4,
    const float* __restrict__ fc1w, const float* __restrict__ fc1b,
    const float* __restrict__ fc2w, const float* __restrict__ fc2b,
    const float* __restrict__ embw, const float* __restrict__ embb,
    const float* __restrict__ wq, const float* __restrict__ bq,
    const float* __restrict__ wk, const float* __restrict__ bk,
    const float* __restrict__ wv, const float* __restrict__ bv,
    float* __restrict__ zt_g, float* __restrict__ q_g,
    float* __restrict__ k_g, float* __restrict__ v_g)
{
  __shared__ __align__(16) float sA[3854];   // win(47x82) -> buf2(8x13x22) -> feat(400)
  __shared__ __align__(16) float sB[4032];   // buf1(4x24x42) -> buf3(16x7x12) -> h1/zp/zt
  __shared__ __align__(16) float sW[5084];
  const int tid = threadIdx.x;
  const int blk = blockIdx.x;
  const int b = blk / LSEQ, i = blk % LSEQ;

  // stage conv weights (padded 9->12) + biases
  for (int t=tid; t<4*9;   t+=256) sW[        (t/9)*12 + t%9] = cw1[t];
  for (int t=tid; t<32*9;  t+=256) sW[  48 +  (t/9)*12 + t%9] = cw2[t];
  for (int t=tid; t<128*9; t+=256) sW[ 432 +  (t/9)*12 + t%9] = cw3[t];
  for (int t=tid; t<256*9; t+=256) sW[1968 +  (t/9)*12 + t%9] = cw4[t];
  if (tid < 4)  sW[5040+tid] = cb1[tid];
  if (tid < 8)  sW[5044+tid] = cb2[tid];
  if (tid < 16) sW[5052+tid] = cb3[tid];
  if (tid < 16) sW[5068+tid] = cb4[tid];

  // window extraction into zero-padded 47x82 tile (right-aligned real frames)
  const int wend = min(i + WHALF + 1, LSEQ);
  const int svalid = max(i - WHALF, 0);
  for (int t=tid; t<47*82; t+=256){
    int r = t/82, c = t%82;
    int j = r-1, d = c-1;
    float val = 0.f;
    if (j>=0 && j<UWIN && d>=0 && d<DDOP){
      int idx = wend - UWIN + j;
      if (idx >= svalid) val = z[(b*LSEQ + idx)*DDOP + d];
    }
    sA[t] = val;
  }
  __syncthreads();

  conv_pool<1, 4,45,80,2,2,true >(sA, sB, sW+0,    sW+5040, tid);  __syncthreads();
  conv_pool<4, 8,22,40,2,2,true >(sB, sA, sW+48,   sW+5044, tid);  __syncthreads();
  conv_pool<8,16,11,20,2,2,true >(sA, sB, sW+432,  sW+5052, tid);  __syncthreads();
  conv_pool<16,16, 5,10,1,2,false>(sB, sA, sW+1968, sW+5068, tid); __syncthreads();
  // feat[400] now in sA

  // fc1: 400 -> 128, ELU
  if (tid < 128){
    const float4* wr4 = (const float4*)(fc1w + tid*400);
    const float4* fr4 = (const float4*)sA;
    float acc = fc1b[tid];
    #pragma unroll 4
    for (int j=0;j<100;++j){ float4 w=wr4[j]; float4 f=fr4[j];
      acc += w.x*f.x + w.y*f.y + w.z*f.z + w.w*f.w; }
    sB[tid] = eluf(acc);
  }
  __syncthreads();
  // fc2: 128 -> 40 (no activation)
  if (tid < 40){
    float acc = fc2b[tid];
    const float* w = fc2w + tid*128;
    #pragma unroll 8
    for (int j=0;j<128;++j) acc += w[j]*sB[j];
    sB[128+tid] = acc;
  }
  __syncthreads();
  // emb: [z_p(40), onehot(5)] -> 40, ELU
  if (tid < 40){
    float acc = embb[tid];
    const float* w = embw + tid*45;
    #pragma unroll 8
    for (int j=0;j<40;++j) acc += w[j]*sB[128+j];
    #pragma unroll
    for (int j=0;j<5;++j)  acc += w[40+j]*toh[b*5+j];
    float ztv = eluf(acc);
    sB[168+tid] = ztv;
    zt_g[blk*40+tid] = ztv;
  }
  __syncthreads();
  // q,k,v: 40 -> 40 each
  if (tid < 120){
    const int which = tid/40, o = tid%40;
    const float* w  = which==0 ? wq : (which==1 ? wk : wv);
    const float* bb = which==0 ? bq : (which==1 ? bk : bv);
    float acc = bb[o];
    const float* wrow = w + o*40;
    #pragma unroll 8
    for (int j=0;j<40;++j) acc += wrow[j]*sB[168+j];
    float* dst = which==0 ? q_g : (which==1 ? k_g : v_g);
    dst[blk*40+o] = acc;
  }
}

__global__ __launch_bounds__(256) void attn_kernel(
    const float* __restrict__ q_g, const float* __restrict__ k_g,
    const float* __restrict__ v_g, const float* __restrict__ zt_g,
    const int* __restrict__ dur,
    const float* __restrict__ flw1, const float* __restrict__ flb1,
    const float* __restrict__ flw2, const float* __restrict__ flb2,
    const float* __restrict__ stw1, const float* __restrict__ stb1,
    const float* __restrict__ stw2, const float* __restrict__ stb2,
    const float* __restrict__ edw1, const float* __restrict__ edb1,
    const float* __restrict__ edw2, const float* __restrict__ edb2,
    float* __restrict__ out)
{
  __shared__ __align__(16) float qrow[40];
  __shared__ __align__(16) float ztr[40];
  __shared__ __align__(16) float esm[900];
  __shared__ float red[256];
  __shared__ float part[6][40];
  __shared__ float xr[40];
  __shared__ float hb[30];

  const int tid = threadIdx.x;
  const int blk = blockIdx.x;
  const int b = blk / LSEQ, i = blk % LSEQ;
  const int durb = dur[b];
  const bool rowv = (i < durb);

  if (tid < 40){ qrow[tid] = q_g[blk*40+tid]; ztr[tid] = zt_g[blk*40+tid]; }
  __syncthreads();

  const float scale = 0.15811388300841897f;   // 1/sqrt(40)
  float lmax = -3.4e38f;
  for (int m = tid; m < LSEQ; m += 256){
    float s;
    if (rowv && m < durb){
      const float4* kr = (const float4*)(k_g + (b*LSEQ+m)*40);
      float acc = 0.f;
      #pragma unroll
      for (int j=0;j<10;++j){ float4 kv = kr[j];
        acc += kv.x*qrow[4*j] + kv.y*qrow[4*j+1] + kv.z*qrow[4*j+2] + kv.w*qrow[4*j+3]; }
      s = acc*scale;
    } else s = -1e-12f;   // exact reference mask value
    esm[m] = s;
    lmax = fmaxf(lmax, s);
  }
  red[tid] = lmax; __syncthreads();
  for (int st=128; st>0; st>>=1){ if (tid<st) red[tid]=fmaxf(red[tid],red[tid+st]); __syncthreads(); }
  const float mx = red[0];
  __syncthreads();

  float lsum = 0.f;
  for (int m = tid; m < LSEQ; m += 256){ float e = expf(esm[m]-mx); esm[m] = e; lsum += e; }
  red[tid] = lsum; __syncthreads();
  for (int st=128; st>0; st>>=1){ if (tid<st) red[tid]+=red[tid+st]; __syncthreads(); }
  const float den = red[0];
  __syncthreads();

  // x = (attn @ v): 6 chunks of 150 rows, 40 dims
  if (tid < 240){
    const int c = tid/40, d = tid%40;
    float acc = 0.f;
    const int m0 = c*150;
    for (int m=m0; m<m0+150; ++m) acc += esm[m]*v_g[(b*LSEQ+m)*40+d];
    part[c][d] = acc;
  }
  __syncthreads();
  if (tid < 40){
    float xv = 0.f;
    #pragma unroll
    for (int c=0;c<6;++c) xv += part[c][tid];
    xr[tid] = xv/den + ztr[tid];   // residual
  }
  __syncthreads();
  // three heads: 40 -> 10 (ELU) -> 1
  if (tid < 30){
    const int hd = tid/10, j = tid%10;
    const float* w1 = hd==0?flw1:(hd==1?stw1:edw1);
    const float* b1 = hd==0?flb1:(hd==1?stb1:edb1);
    float a = b1[j];
    #pragma unroll 8
    for (int d=0; d<40; ++d) a += w1[j*40+d]*xr[d];
    hb[tid] = eluf(a);
  }
  __syncthreads();
  if (tid < 3){
    const float* w2 = tid==0?flw2:(tid==1?stw2:edw2);
    const float* b2 = tid==0?flb2:(tid==1?stb2:edb2);
    float a = b2[0];
    #pragma unroll
    for (int j=0;j<10;++j) a += w2[j]*hb[tid*10+j];
    out[tid*NWIN + blk] = a;
  }
}

extern "C" void kernel_launch(void* const* d_in, const int* in_sizes, int n_in,
                              void* d_out, int out_size, void* d_ws, size_t ws_size,
                              hipStream_t stream) {
  const float* z    = (const float*)d_in[0];
  const float* toh  = (const float*)d_in[1];
  const int*   dur  = (const int*)d_in[2];
  const float* cw1  = (const float*)d_in[3];
  const float* cb1  = (const float*)d_in[4];
  const float* cw2  = (const float*)d_in[5];
  const float* cb2  = (const float*)d_in[6];
  const float* cw3  = (const float*)d_in[7];
  const float* cb3  = (const float*)d_in[8];
  const float* cw4  = (const float*)d_in[9];
  const float* cb4  = (const float*)d_in[10];
  const float* fc1w = (const float*)d_in[11];
  const float* fc1b = (const float*)d_in[12];
  const float* fc2w = (const float*)d_in[13];
  const float* fc2b = (const float*)d_in[14];
  const float* embw = (const float*)d_in[15];
  const float* embb = (const float*)d_in[16];
  const float* wq   = (const float*)d_in[17];
  const float* bq   = (const float*)d_in[18];
  const float* wk   = (const float*)d_in[19];
  const float* bk   = (const float*)d_in[20];
  const float* wv   = (const float*)d_in[21];
  const float* bv   = (const float*)d_in[22];
  const float* flw1 = (const float*)d_in[23];
  const float* flb1 = (const float*)d_in[24];
  const float* flw2 = (const float*)d_in[25];
  const float* flb2 = (const float*)d_in[26];
  const float* stw1 = (const float*)d_in[27];
  const float* stb1 = (const float*)d_in[28];
  const float* stw2 = (const float*)d_in[29];
  const float* stb2 = (const float*)d_in[30];
  const float* edw1 = (const float*)d_in[31];
  const float* edb1 = (const float*)d_in[32];
  const float* edw2 = (const float*)d_in[33];
  const float* edb2 = (const float*)d_in[34];

  float* ws = (float*)d_ws;
  float* zt = ws;                  // 3600*40
  float* q  = ws + 144000;
  float* k  = ws + 288000;
  float* v  = ws + 432000;

  encoder_kernel<<<NWIN, 256, 0, stream>>>(z, toh, cw1,cb1, cw2,cb2, cw3,cb3, cw4,cb4,
                                           fc1w,fc1b, fc2w,fc2b, embw,embb,
                                           wq,bq, wk,bk, wv,bv, zt, q, k, v);
  attn_kernel<<<NWIN, 256, 0, stream>>>(q, k, v, zt, dur,
                                        flw1,flb1,flw2,flb2,
                                        stw1,stb1,stw2,stb2,
                                        edw1,edb1,edw2,edb2,
                                        (float*)d_out);
}

// Round 2
// 216.805 us; speedup vs baseline: 1.2925x; 1.2925x over previous
//
#include <hip/hip_runtime.h>

typedef unsigned int u32;
typedef _Float16 f16;
typedef f16 f16x2 __attribute__((ext_vector_type(2)));

#define LSEQ 900
#define BATCH 4
#define NWIN (BATCH*LSEQ)
#define WPB 4
#define NBLKS (NWIN/WPB)   // 900

#if defined(__has_builtin)
#if __has_builtin(__builtin_amdgcn_fdot2)
#define HAS_FDOT2 1
#endif
#endif

__device__ __forceinline__ float dot2f(f16x2 a, f16x2 b, float c){
#ifdef HAS_FDOT2
  return __builtin_amdgcn_fdot2(a, b, c, false);
#else
  return c + (float)a.x*(float)b.x + (float)a.y*(float)b.y;
#endif
}
__device__ __forceinline__ float eluf(float x){ return x > 0.f ? x : expm1f(x); }
__device__ __forceinline__ u32 pkh(float a, float b){ f16x2 h; h.x = (f16)a; h.y = (f16)b; return __builtin_bit_cast(u32, h); }
#define BC2(u) __builtin_bit_cast(f16x2, (u))

// ---- LDS layout (u32 words) ----
// SWP  [0,5040)    packed f16 conv weights (per (oc,ic): 3 rows x {w01,w20,w12,w00})
// SBIAS[5040,5084) f32 conv biases (cb1:0..4, cb2:4..12, cb3:12..28, cb4:28..44)
// BUFA [5088,13536)  4 wins x 2112: stage1 out [4ch][24][44]h ; later buf3 [16][7][14]h (784 u32) + featH 400h (200 u32) @ +784
// BUFB [13536,18944) 4 wins x 1352: stage2 out [8ch][13][26]h
// H1   [18944,19456) 4 x 128 f32
// ZP   [19456,19616) 4 x 40 f32
// ZT   [19616,19776) 4 x 40 f32
enum : int { SWP = 0, SBIAS = 5040, BUFA = 5088, BUFB = 13536, H1F = 18944, ZPF = 19456, ZTF = 19616, STOT = 19776 };

// ---- prep: pack conv weights + fc1 weights to f16 pairs in workspace ----
__global__ __launch_bounds__(256) void prep_kernel(
    const float* __restrict__ cw1, const float* __restrict__ cw2,
    const float* __restrict__ cw3, const float* __restrict__ cw4,
    const float* __restrict__ fc1w, u32* __restrict__ wsPack, u32* __restrict__ wsFc1h)
{
  const int tid = threadIdx.x;
  if (blockIdx.x == 0) {
    for (int r = tid; r < 1260; r += 256) {   // 420 (oc,ic) entries x 3 rows
      const int e = r / 3, dr = r % 3;
      const float* src; int base;
      if (e < 4)        { src = cw1 + e*9;        base = 0    + e*12; }
      else if (e < 36)  { src = cw2 + (e-4)*9;    base = 48   + (e-4)*12; }
      else if (e < 164) { src = cw3 + (e-36)*9;   base = 432  + (e-36)*12; }
      else              { src = cw4 + (e-164)*9;  base = 1968 + (e-164)*12; }
      const float w0 = src[dr*3], w1 = src[dr*3+1], w2 = src[dr*3+2];
      u32* d = wsPack + base + dr*4;
      d[0] = pkh(w0, w1); d[1] = pkh(w2, 0.f); d[2] = pkh(w1, w2); d[3] = pkh(w0, 0.f);
    }
  } else {
    const int g = (blockIdx.x - 1)*256 + tid;   // 0..25599 (128x400 / 2)
    wsFc1h[g] = pkh(fc1w[2*g], fc1w[2*g+1]);
  }
}

// ---- generic conv3x3 + ELU + pool2x2 stage on f16 LDS buffers (per-thread: OCT oc x 1 loc x 4 windows) ----
template<int IC, int OC, int OCT, int PH, int PW,
         int IROWS, int ISTR, int ORO, int OSTR,
         int WB, int BOFF, int INW, int OUTW>
__device__ __forceinline__ void conv22(u32* sm, const u32* inb, u32* outb, int tid)
{
  constexpr int NOCG = OC / OCT;       // must divide 256 for slot stability
  constexpr int NSLOT = PH*PW*NOCG;
  const uint4* wp = (const uint4*)(sm + SWP);
  const float* bias = (const float*)(sm + SBIAS);
  for (int sl = tid; sl < NSLOT; sl += 256) {
    const int ocg = sl % NOCG;
    const int loc = sl / NOCG;
    const int pr = loc / PW, pc = loc % PW;
    float acc[WPB][OCT][2][2];
    #pragma unroll
    for (int w = 0; w < WPB; ++w)
      #pragma unroll
      for (int j = 0; j < OCT; ++j) {
        const float bv = bias[BOFF + ocg*OCT + j];
        acc[w][j][0][0] = bv; acc[w][j][0][1] = bv; acc[w][j][1][0] = bv; acc[w][j][1][1] = bv;
      }
    for (int ic = 0; ic < IC; ++ic) {
      f16x2 A[WPB][4], B[WPB][4], H[WPB][4];
      #pragma unroll
      for (int w = 0; w < WPB; ++w) {
        const u32* ib = inb + w*INW;
        #pragma unroll
        for (int rr = 0; rr < 4; ++rr) {
          const int idx = ((ic*IROWS + 2*pr + rr)*ISTR + 2*pc) >> 1;  // even: ISTR even, 2pc even
          const u32 av = ib[idx], bv2 = ib[idx+1];
          A[w][rr] = BC2(av); B[w][rr] = BC2(bv2);
          H[w][rr] = __builtin_shufflevector(A[w][rr], A[w][rr], 1, 1);
        }
      }
      #pragma unroll
      for (int j = 0; j < OCT; ++j) {
        const int oc = ocg*OCT + j;
        const uint4* we = wp + (WB + (oc*IC + ic)*12)/4;
        const uint4 r0 = we[0], r1 = we[1], r2 = we[2];
        f16x2 W01[3] = {BC2(r0.x), BC2(r1.x), BC2(r2.x)};
        f16x2 W20[3] = {BC2(r0.y), BC2(r1.y), BC2(r2.y)};
        f16x2 W12[3] = {BC2(r0.z), BC2(r1.z), BC2(r2.z)};
        f16x2 W00[3] = {BC2(r0.w), BC2(r1.w), BC2(r2.w)};
        #pragma unroll
        for (int w = 0; w < WPB; ++w)
          #pragma unroll
          for (int a = 0; a < 2; ++a)
            #pragma unroll
            for (int dr = 0; dr < 3; ++dr) {
              const f16x2 pa = A[w][a+dr], pb = B[w][a+dr], ph = H[w][a+dr];
              acc[w][j][a][0] = dot2f(pa, W01[dr], acc[w][j][a][0]);
              acc[w][j][a][0] = dot2f(pb, W20[dr], acc[w][j][a][0]);
              acc[w][j][a][1] = dot2f(ph, W00[dr], acc[w][j][a][1]);
              acc[w][j][a][1] = dot2f(pb, W12[dr], acc[w][j][a][1]);
            }
      }
    }
    #pragma unroll
    for (int w = 0; w < WPB; ++w) {
      f16* ob = (f16*)(outb + w*OUTW);
      #pragma unroll
      for (int j = 0; j < OCT; ++j) {
        const int oc = ocg*OCT + j;
        const float m = fmaxf(fmaxf(acc[w][j][0][0], acc[w][j][0][1]),
                              fmaxf(acc[w][j][1][0], acc[w][j][1][1]));
        ob[(oc*ORO + pr + 1)*OSTR + (pc + 1)] = (f16)eluf(m);
      }
    }
  }
}

__global__ __launch_bounds__(256) void encoder2(
    const float* __restrict__ z, const float* __restrict__ toh,
    const float* __restrict__ cw1, const float* __restrict__ cb1,
    const float* __restrict__ cb2, const float* __restrict__ cb3, const float* __restrict__ cb4,
    const u32* __restrict__ wsPack, const u32* __restrict__ wsFc1h,
    const float* __restrict__ fc1b, const float* __restrict__ fc2w, const float* __restrict__ fc2b,
    const float* __restrict__ embw, const float* __restrict__ embb,
    const float* __restrict__ wq, const float* __restrict__ bq,
    const float* __restrict__ wk, const float* __restrict__ bk,
    const float* __restrict__ wv, const float* __restrict__ bv,
    float* __restrict__ zt_g, float* __restrict__ q_g,
    float* __restrict__ k_g, float* __restrict__ v_g)
{
  __shared__ __align__(16) u32 sm[STOT];
  const int tid = threadIdx.x;
  const int blk = blockIdx.x;
  const int b = blk / (NBLKS/BATCH);          // 225 blocks per batch
  const int i0 = (blk % (NBLKS/BATCH)) * WPB;
  const float* zb = z + b*LSEQ*80;

  // stage weights, biases; zero both buffer regions
  for (int t = tid; t < 5040; t += 256) sm[t] = wsPack[t];
  {
    float* bf = (float*)(sm + SBIAS);
    if (tid < 44) {
      float v;
      if (tid < 4) v = cb1[tid];
      else if (tid < 12) v = cb2[tid-4];
      else if (tid < 28) v = cb3[tid-12];
      else v = cb4[tid-28];
      bf[tid] = v;
    }
  }
  {
    const uint4 z4 = make_uint4(0,0,0,0);
    uint4* p = (uint4*)(sm + BUFA);
    for (int k = tid; k < (13536+5408-BUFA)/4; k += 256) p[k] = z4;  // BUFA..18944
  }
  __syncthreads();

  // ---- stage1: z(global, masked window) -> conv3x3 x4oc + pool2x2 + elu -> BUFA f16 [4][24][44] ----
  {
    float w1r[36];
    #pragma unroll
    for (int t = 0; t < 36; ++t) w1r[t] = cw1[t];
    float b1[4] = {cb1[0], cb1[1], cb1[2], cb1[3]};
    int e45[WPB], sv[WPB];
    #pragma unroll
    for (int w = 0; w < WPB; ++w) {
      const int i = i0 + w;
      e45[w] = min(i + 23, LSEQ) - 45;
      sv[w]  = max(i - 22, 0);
    }
    for (int s = tid; s < 880; s += 256) {       // 22 x 40 pooled locs
      const int pr = s / 40, pc = s % 40;
      #pragma unroll
      for (int w = 0; w < WPB; ++w) {
        float p[4][4];
        #pragma unroll
        for (int rr = 0; rr < 4; ++rr) {
          const int R = 2*pr - 1 + rr;
          const int f = e45[w] + R;
          const bool rok = (R >= 0) && (f >= sv[w]);
          #pragma unroll
          for (int cc = 0; cc < 4; ++cc) {
            const int c = 2*pc - 1 + cc;
            p[rr][cc] = (rok && c >= 0 && c < 80) ? zb[f*80 + c] : 0.f;
          }
        }
        f16* ob = (f16*)(sm + BUFA + w*2112);
        #pragma unroll
        for (int oc = 0; oc < 4; ++oc) {
          float v00 = b1[oc], v01 = b1[oc], v10 = b1[oc], v11 = b1[oc];
          #pragma unroll
          for (int dr = 0; dr < 3; ++dr)
            #pragma unroll
            for (int dc = 0; dc < 3; ++dc) {
              const float wv2 = w1r[oc*9 + dr*3 + dc];
              v00 += wv2 * p[dr][dc];   v01 += wv2 * p[dr][dc+1];
              v10 += wv2 * p[dr+1][dc]; v11 += wv2 * p[dr+1][dc+1];
            }
          const float m = fmaxf(fmaxf(v00, v01), fmaxf(v10, v11));
          ob[(oc*24 + pr + 1)*44 + (pc + 1)] = (f16)eluf(m);
        }
      }
    }
  }
  __syncthreads();

  // ---- stage2: BUFA [4][24][44] -> BUFB [8][13][26] ----
  conv22<4, 8, 4, 11, 20, 24, 44, 13, 26, 48, 4, 2112, 1352>(sm, sm + BUFA, sm + BUFB, tid);
  __syncthreads();

  // zero buf3 regions (re-use BUFA win regions [0,784) u32)
  {
    const uint4 z4 = make_uint4(0,0,0,0);
    for (int k = tid; k < 784; k += 256) {      // 4 wins x 196 uint4
      const int w = k / 196, o = k % 196;
      ((uint4*)(sm + BUFA + w*2112))[o] = z4;
    }
  }
  __syncthreads();

  // ---- stage3: BUFB [8][13][26] -> buf3 in BUFA [16][7][14] ----
  conv22<8, 16, 4, 5, 10, 13, 26, 7, 14, 432, 12, 1352, 2112>(sm, sm + BUFB, sm + BUFA, tid);
  __syncthreads();

  // ---- stage4: buf3 [16][7][14] -> conv3x3 + pool1x2 + elu -> featH (f16[400] @ BUFA+784) ----
  if (tid < 100) {
    const int ocg = tid % 4;
    const int loc = tid / 4;
    const int pr = loc / 5, pc = loc % 5;
    const uint4* wp = (const uint4*)(sm + SWP);
    const float* bias = (const float*)(sm + SBIAS);
    float accE[WPB][4], accO[WPB][4];
    #pragma unroll
    for (int w = 0; w < WPB; ++w)
      #pragma unroll
      for (int j = 0; j < 4; ++j) { const float bv = bias[28 + ocg*4 + j]; accE[w][j] = bv; accO[w][j] = bv; }
    for (int ic = 0; ic < 16; ++ic) {
      f16x2 A[WPB][3], B[WPB][3], H[WPB][3];
      #pragma unroll
      for (int w = 0; w < WPB; ++w) {
        const u32* ib = sm + BUFA + w*2112;
        #pragma unroll
        for (int rr = 0; rr < 3; ++rr) {
          const int idx = ((ic*7 + pr + rr)*14 + 2*pc) >> 1;
          const u32 av = ib[idx], bv2 = ib[idx+1];
          A[w][rr] = BC2(av); B[w][rr] = BC2(bv2);
          H[w][rr] = __builtin_shufflevector(A[w][rr], A[w][rr], 1, 1);
        }
      }
      #pragma unroll
      for (int j = 0; j < 4; ++j) {
        const int oc = ocg*4 + j;
        const uint4* we = wp + (1968 + (oc*16 + ic)*12)/4;
        const uint4 r0 = we[0], r1 = we[1], r2 = we[2];
        f16x2 W01[3] = {BC2(r0.x), BC2(r1.x), BC2(r2.x)};
        f16x2 W20[3] = {BC2(r0.y), BC2(r1.y), BC2(r2.y)};
        f16x2 W12[3] = {BC2(r0.z), BC2(r1.z), BC2(r2.z)};
        f16x2 W00[3] = {BC2(r0.w), BC2(r1.w), BC2(r2.w)};
        #pragma unroll
        for (int w = 0; w < WPB; ++w)
          #pragma unroll
          for (int dr = 0; dr < 3; ++dr) {
            accE[w][j] = dot2f(A[w][dr], W01[dr], accE[w][j]);
            accE[w][j] = dot2f(B[w][dr], W20[dr], accE[w][j]);
            accO[w][j] = dot2f(H[w][dr], W00[dr], accO[w][j]);
            accO[w][j] = dot2f(B[w][dr], W12[dr], accO[w][j]);
          }
      }
    }
    #pragma unroll
    for (int w = 0; w < WPB; ++w) {
      f16* fh = (f16*)(sm + BUFA + w*2112 + 784);
      #pragma unroll
      for (int j = 0; j < 4; ++j) {
        const int oc = ocg*4 + j;
        fh[oc*25 + pr*5 + pc] = (f16)eluf(fmaxf(accE[w][j], accO[w][j]));
      }
    }
  }
  __syncthreads();

  // ---- fc1: feat(f16,400) x fc1w(f16,global) -> h1 f32[4][128], elu ----
  {
    const int n = tid & 127, wg = tid >> 7;
    float a0 = fc1b[n], a1 = a0;
    const uint4* wrow = (const uint4*)(wsFc1h + n*200);
    const uint4* f0 = (const uint4*)(sm + BUFA + (wg*2    )*2112 + 784);
    const uint4* f1 = (const uint4*)(sm + BUFA + (wg*2 + 1)*2112 + 784);
    for (int c = 0; c < 50; ++c) {
      const uint4 wv2 = wrow[c]; const uint4 fa = f0[c]; const uint4 fb = f1[c];
      a0 = dot2f(BC2(wv2.x), BC2(fa.x), a0); a0 = dot2f(BC2(wv2.y), BC2(fa.y), a0);
      a0 = dot2f(BC2(wv2.z), BC2(fa.z), a0); a0 = dot2f(BC2(wv2.w), BC2(fa.w), a0);
      a1 = dot2f(BC2(wv2.x), BC2(fb.x), a1); a1 = dot2f(BC2(wv2.y), BC2(fb.y), a1);
      a1 = dot2f(BC2(wv2.z), BC2(fb.z), a1); a1 = dot2f(BC2(wv2.w), BC2(fb.w), a1);
    }
    float* h1 = (float*)(sm + H1F);
    h1[(wg*2)*128 + n] = eluf(a0);
    h1[(wg*2+1)*128 + n] = eluf(a1);
  }
  __syncthreads();

  // ---- fc2: h1[128] -> zp[40] (no act) ----
  if (tid < 160) {
    const int w = tid / 40, n = tid % 40;
    const float* h1 = (float*)(sm + H1F) + w*128;
    const float4* hv = (const float4*)h1;
    const float4* wr = (const float4*)(fc2w + n*128);
    float acc = fc2b[n];
    #pragma unroll 8
    for (int c = 0; c < 32; ++c) {
      const float4 a = wr[c], x = hv[c];
      acc += a.x*x.x + a.y*x.y + a.z*x.z + a.w*x.w;
    }
    ((float*)(sm + ZPF))[w*40 + n] = acc;
  }
  __syncthreads();

  // ---- emb: [zp(40), onehot(5)] -> zt[40], elu ----
  if (tid < 160) {
    const int w = tid / 40, n = tid % 40;
    const float* zp = (float*)(sm + ZPF) + w*40;
    const float* wr = embw + n*45;
    float acc = embb[n];
    #pragma unroll 8
    for (int j = 0; j < 40; ++j) acc += wr[j]*zp[j];
    #pragma unroll
    for (int j = 0; j < 5; ++j)  acc += wr[40+j]*toh[b*5 + j];
    const float v2 = eluf(acc);
    ((float*)(sm + ZTF))[w*40 + n] = v2;
    zt_g[(b*LSEQ + i0 + w)*40 + n] = v2;
  }
  __syncthreads();

  // ---- q,k,v ----
  for (int s = tid; s < 480; s += 256) {
    const int which = s / 160, r = s % 160, w = r / 40, n = r % 40;
    const float* wm = which == 0 ? wq : (which == 1 ? wk : wv);
    const float* bb = which == 0 ? bq : (which == 1 ? bk : bv);
    const float4* wr = (const float4*)(wm + n*40);
    const float4* zv = (const float4*)((float*)(sm + ZTF) + w*40);
    float acc = bb[n];
    #pragma unroll
    for (int c = 0; c < 10; ++c) {
      const float4 a = wr[c], x = zv[c];
      acc += a.x*x.x + a.y*x.y + a.z*x.z + a.w*x.w;
    }
    float* dst = which == 0 ? q_g : (which == 1 ? k_g : v_g);
    dst[(b*LSEQ + i0 + w)*40 + n] = acc;
  }
}

__global__ __launch_bounds__(256) void attn_kernel(
    const float* __restrict__ q_g, const float* __restrict__ k_g,
    const float* __restrict__ v_g, const float* __restrict__ zt_g,
    const int* __restrict__ dur,
    const float* __restrict__ flw1, const float* __restrict__ flb1,
    const float* __restrict__ flw2, const float* __restrict__ flb2,
    const float* __restrict__ stw1, const float* __restrict__ stb1,
    const float* __restrict__ stw2, const float* __restrict__ stb2,
    const float* __restrict__ edw1, const float* __restrict__ edb1,
    const float* __restrict__ edw2, const float* __restrict__ edb2,
    float* __restrict__ out)
{
  __shared__ __align__(16) float qrow[40];
  __shared__ __align__(16) float ztr[40];
  __shared__ __align__(16) float esm[900];
  __shared__ float red[256];
  __shared__ float part[6][40];
  __shared__ float xr[40];
  __shared__ float hb[30];

  const int tid = threadIdx.x;
  const int blk = blockIdx.x;
  const int b = blk / LSEQ, i = blk % LSEQ;
  const int durb = dur[b];
  const bool rowv = (i < durb);

  if (tid < 40){ qrow[tid] = q_g[blk*40+tid]; ztr[tid] = zt_g[blk*40+tid]; }
  __syncthreads();

  const float scale = 0.15811388300841897f;   // 1/sqrt(40)
  float lmax = -3.4e38f;
  for (int m = tid; m < LSEQ; m += 256){
    float s;
    if (rowv && m < durb){
      const float4* kr = (const float4*)(k_g + (b*LSEQ+m)*40);
      float acc = 0.f;
      #pragma unroll
      for (int j=0;j<10;++j){ float4 kv = kr[j];
        acc += kv.x*qrow[4*j] + kv.y*qrow[4*j+1] + kv.z*qrow[4*j+2] + kv.w*qrow[4*j+3]; }
      s = acc*scale;
    } else s = -1e-12f;   // exact reference mask value
    esm[m] = s;
    lmax = fmaxf(lmax, s);
  }
  red[tid] = lmax; __syncthreads();
  for (int st=128; st>0; st>>=1){ if (tid<st) red[tid]=fmaxf(red[tid],red[tid+st]); __syncthreads(); }
  const float mx = red[0];
  __syncthreads();

  float lsum = 0.f;
  for (int m = tid; m < LSEQ; m += 256){ float e = expf(esm[m]-mx); esm[m] = e; lsum += e; }
  red[tid] = lsum; __syncthreads();
  for (int st=128; st>0; st>>=1){ if (tid<st) red[tid]+=red[tid+st]; __syncthreads(); }
  const float den = red[0];
  __syncthreads();

  if (tid < 240){
    const int c = tid/40, d = tid%40;
    float acc = 0.f;
    const int m0 = c*150;
    for (int m=m0; m<m0+150; ++m) acc += esm[m]*v_g[(b*LSEQ+m)*40+d];
    part[c][d] = acc;
  }
  __syncthreads();
  if (tid < 40){
    float xv = 0.f;
    #pragma unroll
    for (int c=0;c<6;++c) xv += part[c][tid];
    xr[tid] = xv/den + ztr[tid];
  }
  __syncthreads();
  if (tid < 30){
    const int hd = tid/10, j = tid%10;
    const float* w1 = hd==0?flw1:(hd==1?stw1:edw1);
    const float* b1 = hd==0?flb1:(hd==1?stb1:edb1);
    float a = b1[j];
    #pragma unroll 8
    for (int d=0; d<40; ++d) a += w1[j*40+d]*xr[d];
    hb[tid] = eluf(a);
  }
  __syncthreads();
  if (tid < 3){
    const float* w2 = tid==0?flw2:(tid==1?stw2:edw2);
    const float* b2 = tid==0?flb2:(tid==1?stb2:edb2);
    float a = b2[0];
    #pragma unroll
    for (int j=0;j<10;++j) a += w2[j]*hb[tid*10+j];
    out[tid*NWIN + blk] = a;
  }
}

extern "C" void kernel_launch(void* const* d_in, const int* in_sizes, int n_in,
                              void* d_out, int out_size, void* d_ws, size_t ws_size,
                              hipStream_t stream) {
  const float* z    = (const float*)d_in[0];
  const float* toh  = (const float*)d_in[1];
  const int*   dur  = (const int*)d_in[2];
  const float* cw1  = (const float*)d_in[3];
  const float* cb1  = (const float*)d_in[4];
  const float* cw2  = (const float*)d_in[5];
  const float* cb2  = (const float*)d_in[6];
  const float* cw3  = (const float*)d_in[7];
  const float* cb3  = (const float*)d_in[8];
  const float* cw4  = (const float*)d_in[9];
  const float* cb4  = (const float*)d_in[10];
  const float* fc1w = (const float*)d_in[11];
  const float* fc1b = (const float*)d_in[12];
  const float* fc2w = (const float*)d_in[13];
  const float* fc2b = (const float*)d_in[14];
  const float* embw = (const float*)d_in[15];
  const float* embb = (const float*)d_in[16];
  const float* wq   = (const float*)d_in[17];
  const float* bq   = (const float*)d_in[18];
  const float* wk   = (const float*)d_in[19];
  const float* bk   = (const float*)d_in[20];
  const float* wv   = (const float*)d_in[21];
  const float* bv   = (const float*)d_in[22];
  const float* flw1 = (const float*)d_in[23];
  const float* flb1 = (const float*)d_in[24];
  const float* flw2 = (const float*)d_in[25];
  const float* flb2 = (const float*)d_in[26];
  const float* stw1 = (const float*)d_in[27];
  const float* stb1 = (const float*)d_in[28];
  const float* stw2 = (const float*)d_in[29];
  const float* stb2 = (const float*)d_in[30];
  const float* edw1 = (const float*)d_in[31];
  const float* edb1 = (const float*)d_in[32];
  const float* edw2 = (const float*)d_in[33];
  const float* edb2 = (const float*)d_in[34];

  // ws layout (4B words): [0,5040) packed conv w; [5120,30720) packed fc1w f16;
  // f32: zt @30720, q @174720, k @318720, v @462720 (each 144000) -> 2.43 MB total
  u32*   wsu     = (u32*)d_ws;
  u32*   wsPack  = wsu;
  u32*   wsFc1h  = wsu + 5120;
  float* wsf     = (float*)d_ws;
  float* zt = wsf + 30720;
  float* q  = wsf + 174720;
  float* k  = wsf + 318720;
  float* v  = wsf + 462720;

  prep_kernel<<<101, 256, 0, stream>>>(cw1, cw2, cw3, cw4, fc1w, wsPack, wsFc1h);
  encoder2<<<NBLKS, 256, 0, stream>>>(z, toh, cw1, cb1, cb2, cb3, cb4,
                                      wsPack, wsFc1h, fc1b, fc2w, fc2b, embw, embb,
                                      wq, bq, wk, bk, wv, bv, zt, q, k, v);
  attn_kernel<<<NWIN, 256, 0, stream>>>(q, k, v, zt, dur,
                                        flw1, flb1, flw2, flb2,
                                        stw1, stb1, stw2, stb2,
                                        edw1, edb1, edw2, edb2,
                                        (float*)d_out);
}

// Round 4
// 142.166 us; speedup vs baseline: 1.9710x; 1.5250x over previous
//
#include <hip/hip_runtime.h>

typedef unsigned int u32;
typedef _Float16 f16;
typedef f16 f16x2 __attribute__((ext_vector_type(2)));
typedef f16 f16x4 __attribute__((ext_vector_type(4)));
typedef f16 f16x8 __attribute__((ext_vector_type(8)));
typedef float f32x4 __attribute__((ext_vector_type(4)));

#define LSEQ 900
#define BATCH 4
#define NWIN (BATCH*LSEQ)
#define WPB 2
#define NBLK (NWIN/WPB)   // 1800

__device__ __forceinline__ float eluf(float x){ return x > 0.f ? x : expm1f(x); }
#define BC2(u) __builtin_bit_cast(f16x2, (u))

// ---- LDS map (u32 words) ----
// P0  [0,4224)    : T1 8448 f16 (2x[24][44][4]) -> T2 4992 f16 (2x[13][24][8]) -> T3 3136 f16 (2x[7][14][16])
// P1  [4224,7744) : H2 7040 f16 (2x[22][20][8]) -> H3 3200 f16 (2x[10][10][16])
// FEAT[7744,8160) : 832 f16 (2x416, tail zeros for K-pad)
// F32 [8160,8576) : h1 2x128, zp 2x40, zt 2x40
#define P0U 0
#define P1U 4224
#define FEATU 7744
#define F32U 8160
#define SMTOT 8576
// f16 offsets / strides
#define T1F 0
#define T1W 4224
#define H2F 8448
#define H2W 3520
#define T2F 0
#define T2W 2496
#define H3F 8448
#define H3W 1600
#define T3F 0
#define T3W 1568
#define FEATF 15488
#define FEATW 416

// ---- ws f16 offsets: prepacked B fragments ----
#define WB2A 0        // 512  : stage2 K=32 (dr0,1)
#define WB2B 512      // 256  : stage2 K=16 (dr2)
#define WB3  768      // 1536 : stage3 3 x K=32 (per dr)
#define WB4  2304     // 3072 : stage4 6 x K=32 (dr,half)
#define WFC1 5376     // 53248: fc1 [nt8][st13][lane64][8]
#define WEND 58624
#define FOFF 29312    // f32 word offset where zt/q/k/v live

// ============ prep: pack all B fragments to f16 in workspace ============
__global__ __launch_bounds__(256) void prep2(
    const float* __restrict__ cw2, const float* __restrict__ cw3,
    const float* __restrict__ cw4, const float* __restrict__ fc1w,
    f16* __restrict__ wsF)
{
  const int g = blockIdx.x*256 + threadIdx.x;
  if (g >= WEND) return;
  float val;
  if (g < 512) {                       // B2A: k = dr*16 + dc*4 + ic (dr 0..1)
    const int l = g>>3, j = g&7;
    const int oc = l&15, c = l>>4;
    const int dr = c>>1, dc = 2*(c&1) + (j>>2), ic = j&3;
    val = (oc<8 && dc<3) ? cw2[oc*36 + ic*9 + dr*3 + dc] : 0.f;
  } else if (g < 768) {                // B2B: dr=2, k = dc*4 + ic
    const int u = g-512, l = u>>2, j = u&3;
    const int oc = l&15, dc = l>>4, ic = j;
    val = (oc<8 && dc<3) ? cw2[oc*36 + ic*9 + 6 + dc] : 0.f;
  } else if (g < 2304) {               // B3[dr]: k = dc*8 + ic
    const int u = g-768, dr = u>>9, r = u&511, l = r>>3, j = r&7;
    const int oc = l&15, dc = l>>4, ic = j;
    val = (dc<3) ? cw3[oc*72 + ic*9 + dr*3 + dc] : 0.f;
  } else if (g < 5376) {               // B4[dr*2+h]: k = dcl*16 + ic, dc = h*2+dcl
    const int u = g-2304, v = u>>9, dr = v>>1, h = v&1;
    const int r = u&511, l = r>>3, j = r&7;
    const int oc = l&15, chunk = l>>4;
    const int dcl = chunk>>1, ic = (chunk&1)*8 + j, dc = h*2 + dcl;
    val = (dc<3) ? cw4[oc*144 + ic*9 + dr*3 + dc] : 0.f;
  } else {                             // fc1B: B[k][n], k = st*32 + (l>>4)*8 + j
    const int u = g - WFC1;
    const int j = u&7, l = (u>>3)&63, st = (u>>9)%13, nt = u/(13*512);
    const int k = st*32 + (l>>4)*8 + j, n = nt*16 + (l&15);
    val = (k<400) ? fc1w[n*400 + k] : 0.f;
  }
  wsF[g] = (f16)val;
}

// ============ encoder: stage1 VALU fp32 -> NHWC f16; stages 2-4 + fc1 on MFMA ============
__global__ __launch_bounds__(256,4) void encoder3(
    const float* __restrict__ z, const float* __restrict__ toh,
    const float* __restrict__ cw1, const float* __restrict__ cb1,
    const float* __restrict__ cb2, const float* __restrict__ cb3, const float* __restrict__ cb4,
    const f16* __restrict__ wsF,
    const float* __restrict__ fc1b, const float* __restrict__ fc2w, const float* __restrict__ fc2b,
    const float* __restrict__ embw, const float* __restrict__ embb,
    const float* __restrict__ wq, const float* __restrict__ bq,
    const float* __restrict__ wk, const float* __restrict__ bk,
    const float* __restrict__ wv, const float* __restrict__ bv,
    float* __restrict__ zt_g, float* __restrict__ q_g,
    float* __restrict__ k_g, float* __restrict__ v_g)
{
  __shared__ __align__(16) u32 sm[SMTOT];
  f16* smh = (f16*)sm;
  const int tid = threadIdx.x, blk = blockIdx.x;
  const int lane = tid & 63, wid = tid >> 6;
  const int g0 = blk*WPB;
  const int b = g0/LSEQ, i0 = g0%LSEQ;
  const float* zb = z + b*LSEQ*80;

  // zero T1 + FEAT regions
  {
    const uint4 z4 = {0,0,0,0};
    uint4* p0 = (uint4*)(sm + P0U);
    for (int t = tid; t < 1056; t += 256) p0[t] = z4;
    uint4* pf = (uint4*)(sm + FEATU);
    for (int t = tid; t < 104; t += 256) pf[t] = z4;
  }
  __syncthreads();

  // ---- stage1: masked window conv1(1->4) + pool2x2 + elu -> T1 NHWC [24][44][4] ----
  {
    float w1r[36];
    #pragma unroll
    for (int t = 0; t < 36; ++t) w1r[t] = cw1[t];
    const float b1[4] = {cb1[0], cb1[1], cb1[2], cb1[3]};
    int e45[WPB], sv[WPB];
    #pragma unroll
    for (int w = 0; w < WPB; ++w) {
      const int i = i0 + w;
      e45[w] = min(i + 23, LSEQ) - 45;
      sv[w]  = max(i - 22, 0);
    }
    for (int s = tid; s < 880; s += 256) {
      const int pr = s/40, pc = s%40;
      #pragma unroll
      for (int w = 0; w < WPB; ++w) {
        float p[4][4];
        #pragma unroll
        for (int rr = 0; rr < 4; ++rr) {
          const int R = 2*pr - 1 + rr;
          const int f = e45[w] + R;
          const bool rok = (R >= 0) && (f >= sv[w]);
          #pragma unroll
          for (int cc = 0; cc < 4; ++cc) {
            const int c = 2*pc - 1 + cc;
            p[rr][cc] = (rok && c >= 0 && c < 80) ? zb[f*80 + c] : 0.f;
          }
        }
        f16x4 ov;
        #pragma unroll
        for (int oc = 0; oc < 4; ++oc) {
          float v00=b1[oc], v01=b1[oc], v10=b1[oc], v11=b1[oc];
          #pragma unroll
          for (int dr = 0; dr < 3; ++dr)
            #pragma unroll
            for (int dc = 0; dc < 3; ++dc) {
              const float wv2 = w1r[oc*9 + dr*3 + dc];
              v00 += wv2*p[dr][dc];   v01 += wv2*p[dr][dc+1];
              v10 += wv2*p[dr+1][dc]; v11 += wv2*p[dr+1][dc+1];
            }
          ov[oc] = (f16)eluf(fmaxf(fmaxf(v00,v01), fmaxf(v10,v11)));
        }
        *(f16x4*)(smh + T1F + w*T1W + ((pr+1)*44 + pc+1)*4) = ov;
      }
    }
  }
  __syncthreads();

  // ---- stage2 MFMA: T1 -> conv(4->8) ; hmax -> H2 [22][20][8] ----
  {
    const f16x8 B2a = *(const f16x8*)(wsF + WB2A + lane*8);
    const f16x4 B2b = *(const f16x4*)(wsF + WB2B + lane*4);
    const int oc = lane&15, chunk = lane>>4;
    const float bias2 = (oc<8) ? cb2[oc] : 0.f;
    for (int t = wid; t < 110; t += 4) {
      const int mA = t*16 + oc;          // A-row = lane&15
      const int winA = mA/880, mmA = mA%880;
      const int r2 = mmA/40, c2 = mmA%40;
      const f16* base = smh + T1F + winA*T1W;
      const f16* pA = base + ((r2 + (chunk>>1))*44 + c2 + 2*(chunk&1))*4;
      const f16x4 lo = *(const f16x4*)(pA);
      const f16x4 hi = *(const f16x4*)(pA + 4);
      const f16x8 a8 = __builtin_shufflevector(lo, hi, 0,1,2,3,4,5,6,7);
      f32x4 acc = {bias2, bias2, bias2, bias2};
      acc = __builtin_amdgcn_mfma_f32_16x16x32_f16(a8, B2a, acc, 0, 0, 0);
      const f16x4 a4 = *(const f16x4*)(base + ((r2+2)*44 + c2 + chunk)*4);
      acc = __builtin_amdgcn_mfma_f32_16x16x16f16(a4, B2b, acc, 0, 0, 0);
      if (oc < 8) {
        #pragma unroll
        for (int p = 0; p < 2; ++p) {
          const int mE = t*16 + chunk*4 + 2*p;
          const int winE = mE/880, mmE = mE%880;
          const int rE = mmE/40, cE = mmE%40;
          smh[H2F + winE*H2W + (rE*20 + (cE>>1))*8 + oc] = (f16)fmaxf(acc[2*p], acc[2*p+1]);
        }
      }
    }
  }
  __syncthreads();

  // ---- vertical max + elu: H2 -> T2 NHWC [13][24][8]; zero T2 border ----
  {
    for (int s = tid; s < 624; s += 256) {
      const int win = s/312, id = s%312;
      const int r = id/24, c = id%24;
      if (!(r>=1 && r<=11 && c>=1 && c<=20)) {
        const uint4 z4 = {0,0,0,0};
        *(uint4*)(smh + T2F + win*T2W + (r*24+c)*8) = z4;
      }
    }
    for (int s = tid; s < 1760; s += 256) {
      const int win = s/880, u = s%880;
      const int pr = u/80, rem = u%80, cp = rem/4, op = rem%4;
      const u32* h2 = (const u32*)(smh + H2F + win*H2W);
      const u32 a  = h2[((2*pr  )*20 + cp)*4 + op];
      const u32 b2 = h2[((2*pr+1)*20 + cp)*4 + op];
      const f16x2 av = BC2(a), bv = BC2(b2);
      f16x2 o;
      o.x = (f16)eluf(fmaxf((float)av.x, (float)bv.x));
      o.y = (f16)eluf(fmaxf((float)av.y, (float)bv.y));
      ((u32*)(smh + T2F + win*T2W))[((pr+1)*24 + cp+1)*4 + op] = __builtin_bit_cast(u32, o);
    }
  }
  __syncthreads();

  // ---- stage3 MFMA: T2 -> conv(8->16); hmax -> H3 [10][10][16] ----
  {
    f16x8 B3r[3];
    #pragma unroll
    for (int dr = 0; dr < 3; ++dr) B3r[dr] = *(const f16x8*)(wsF + WB3 + dr*512 + lane*8);
    const int oc = lane&15, chunk = lane>>4;
    const float bias3 = cb3[oc];
    for (int t = wid; t < 28; t += 4) {
      const int mA = t*16 + oc;
      const int winA = mA/220, mmA = mA%220;   // winA may be 2 on pad tiles: reads stale-but-finite LDS, rows discarded
      const int r3 = mmA/20, c3 = mmA%20;
      const f16* base = smh + T2F + min(winA,1)*T2W;
      f32x4 acc = {bias3, bias3, bias3, bias3};
      #pragma unroll
      for (int dr = 0; dr < 3; ++dr) {
        const f16x8 a8 = *(const f16x8*)(base + ((r3+dr)*24 + c3 + chunk)*8);
        acc = __builtin_amdgcn_mfma_f32_16x16x32_f16(a8, B3r[dr], acc, 0, 0, 0);
      }
      #pragma unroll
      for (int p = 0; p < 2; ++p) {
        const int mE = t*16 + chunk*4 + 2*p;
        if (mE < 440) {
          const int winE = mE/220, mmE = mE%220;
          const int rE = mmE/20, cE = mmE%20;
          if (rE < 10)
            smh[H3F + winE*H3W + (rE*10 + (cE>>1))*16 + oc] = (f16)fmaxf(acc[2*p], acc[2*p+1]);
        }
      }
    }
  }
  __syncthreads();

  // ---- vertical max + elu: H3 -> T3 NHWC [7][14][16]; zero T3 border ----
  {
    for (int s = tid; s < 196; s += 256) {
      const int win = s/98, id = s%98;
      const int r = id/14, c = id%14;
      if (!(r>=1 && r<=5 && c>=1 && c<=10)) {
        const uint4 z4 = {0,0,0,0};
        *(uint4*)(smh + T3F + win*T3W + (r*14+c)*16)     = z4;
        *(uint4*)(smh + T3F + win*T3W + (r*14+c)*16 + 8) = z4;
      }
    }
    for (int s = tid; s < 800; s += 256) {
      const int win = s/400, u = s%400;
      const int pr = u/80, rem = u%80, cp = rem/8, op = rem%8;
      const u32* h3 = (const u32*)(smh + H3F + win*H3W);
      const u32 a  = h3[((2*pr  )*10 + cp)*8 + op];
      const u32 b2 = h3[((2*pr+1)*10 + cp)*8 + op];
      const f16x2 av = BC2(a), bv = BC2(b2);
      f16x2 o;
      o.x = (f16)eluf(fmaxf((float)av.x, (float)bv.x));
      o.y = (f16)eluf(fmaxf((float)av.y, (float)bv.y));
      ((u32*)(smh + T3F + win*T3W))[((pr+1)*14 + cp+1)*8 + op] = __builtin_bit_cast(u32, o);
    }
  }
  __syncthreads();

  // ---- stage4 MFMA: T3 -> conv(16->16) + pool1x2 + elu -> feat NCHW f16[400] ----
  {
    f16x8 B4r[6];
    #pragma unroll
    for (int v = 0; v < 6; ++v) B4r[v] = *(const f16x8*)(wsF + WB4 + v*512 + lane*8);
    const int oc = lane&15, chunk = lane>>4;
    const int dcl = chunk>>1, hsel = chunk&1;
    const float bias4 = cb4[oc];
    for (int t = wid; t < 7; t += 4) {
      const int mA = t*16 + oc;
      const int winA = mA/50, mmA = mA%50;
      const int r4 = mmA/10, c4 = mmA%10;
      const f16* base = smh + T3F + min(winA,1)*T3W;
      f32x4 acc = {bias4, bias4, bias4, bias4};
      #pragma unroll
      for (int v = 0; v < 6; ++v) {
        const int dr = v>>1, h = v&1;
        const f16x8 a8 = *(const f16x8*)(base + ((r4+dr)*14 + c4 + h*2 + dcl)*16 + hsel*8);
        acc = __builtin_amdgcn_mfma_f32_16x16x32_f16(a8, B4r[v], acc, 0, 0, 0);
      }
      #pragma unroll
      for (int p = 0; p < 2; ++p) {
        const int mE = t*16 + chunk*4 + 2*p;
        if (mE < 100) {
          const int winE = mE/50, mmE = mE%50;
          const int rE = mmE/10, cE = mmE%10;
          smh[FEATF + winE*FEATW + oc*25 + rE*5 + (cE>>1)] = (f16)eluf(fmaxf(acc[2*p], acc[2*p+1]));
        }
      }
    }
  }
  __syncthreads();

  // ---- fc1 MFMA: feat[2x416] x fc1B -> h1 f32 [2][128], elu ----
  {
    const int col = lane&15, kg = lane>>4;
    const int winc = min(col, 1);
    float* h1 = (float*)(sm + F32U);
    #pragma unroll
    for (int q2 = 0; q2 < 2; ++q2) {
      const int nt = wid + q2*4;
      f32x4 acc = {0.f, 0.f, 0.f, 0.f};
      for (int st = 0; st < 13; ++st) {
        const f16x8 a8 = *(const f16x8*)(smh + FEATF + winc*FEATW + st*32 + kg*8);
        const f16x8 b8 = *(const f16x8*)(wsF + WFC1 + ((nt*13 + st)*64 + lane)*8);
        acc = __builtin_amdgcn_mfma_f32_16x16x32_f16(a8, b8, acc, 0, 0, 0);
      }
      if (lane < 16) {
        const int n = nt*16 + col;
        const float fb = fc1b[n];
        h1[0*128 + n] = eluf(acc[0] + fb);
        h1[1*128 + n] = eluf(acc[1] + fb);
      }
    }
  }
  __syncthreads();

  // ---- fc2 -> emb -> qkv (small VALU) ----
  float* fregion = (float*)(sm + F32U);
  float* h1f = fregion;
  float* zpf = fregion + 256;
  float* ztf = fregion + 336;
  if (tid < 80) {
    const int w = tid/40, n = tid%40;
    const float4* hv = (const float4*)(h1f + w*128);
    const float4* wr = (const float4*)(fc2w + n*128);
    float acc = fc2b[n];
    #pragma unroll 8
    for (int c = 0; c < 32; ++c) {
      const float4 a = wr[c], x = hv[c];
      acc += a.x*x.x + a.y*x.y + a.z*x.z + a.w*x.w;
    }
    zpf[w*40 + n] = acc;
  }
  __syncthreads();
  if (tid < 80) {
    const int w = tid/40, n = tid%40;
    const float* zp = zpf + w*40;
    const float* wr = embw + n*45;
    float acc = embb[n];
    #pragma unroll 8
    for (int j = 0; j < 40; ++j) acc += wr[j]*zp[j];
    #pragma unroll
    for (int j = 0; j < 5; ++j)  acc += wr[40+j]*toh[b*5 + j];
    const float v2 = eluf(acc);
    ztf[w*40 + n] = v2;
    zt_g[(b*LSEQ + i0 + w)*40 + n] = v2;
  }
  __syncthreads();
  if (tid < 240) {
    const int which = tid/80, r = tid%80, w = r/40, n = r%40;
    const float* wm = which==0 ? wq : (which==1 ? wk : wv);
    const float* bb = which==0 ? bq : (which==1 ? bk : bv);
    const float4* wr = (const float4*)(wm + n*40);
    const float4* zv = (const float4*)(ztf + w*40);
    float acc = bb[n];
    #pragma unroll
    for (int c = 0; c < 10; ++c) {
      const float4 a = wr[c], x = zv[c];
      acc += a.x*x.x + a.y*x.y + a.z*x.z + a.w*x.w;
    }
    float* dst = which==0 ? q_g : (which==1 ? k_g : v_g);
    dst[(b*LSEQ + i0 + w)*40 + n] = acc;
  }
}

__global__ __launch_bounds__(256) void attn_kernel(
    const float* __restrict__ q_g, const float* __restrict__ k_g,
    const float* __restrict__ v_g, const float* __restrict__ zt_g,
    const int* __restrict__ dur,
    const float* __restrict__ flw1, const float* __restrict__ flb1,
    const float* __restrict__ flw2, const float* __restrict__ flb2,
    const float* __restrict__ stw1, const float* __restrict__ stb1,
    const float* __restrict__ stw2, const float* __restrict__ stb2,
    const float* __restrict__ edw1, const float* __restrict__ edb1,
    const float* __restrict__ edw2, const float* __restrict__ edb2,
    float* __restrict__ out)
{
  __shared__ __align__(16) float qrow[40];
  __shared__ __align__(16) float ztr[40];
  __shared__ __align__(16) float esm[900];
  __shared__ float red[256];
  __shared__ float part[6][40];
  __shared__ float xr[40];
  __shared__ float hb[30];

  const int tid = threadIdx.x;
  const int blk = blockIdx.x;
  const int b = blk / LSEQ, i = blk % LSEQ;
  const int durb = dur[b];
  const bool rowv = (i < durb);

  if (tid < 40){ qrow[tid] = q_g[blk*40+tid]; ztr[tid] = zt_g[blk*40+tid]; }
  __syncthreads();

  const float scale = 0.15811388300841897f;
  float lmax = -3.4e38f;
  for (int m = tid; m < LSEQ; m += 256){
    float s;
    if (rowv && m < durb){
      const float4* kr = (const float4*)(k_g + (b*LSEQ+m)*40);
      float acc = 0.f;
      #pragma unroll
      for (int j=0;j<10;++j){ float4 kv = kr[j];
        acc += kv.x*qrow[4*j] + kv.y*qrow[4*j+1] + kv.z*qrow[4*j+2] + kv.w*qrow[4*j+3]; }
      s = acc*scale;
    } else s = -1e-12f;
    esm[m] = s;
    lmax = fmaxf(lmax, s);
  }
  red[tid] = lmax; __syncthreads();
  for (int st=128; st>0; st>>=1){ if (tid<st) red[tid]=fmaxf(red[tid],red[tid+st]); __syncthreads(); }
  const float mx = red[0];
  __syncthreads();

  float lsum = 0.f;
  for (int m = tid; m < LSEQ; m += 256){ float e = expf(esm[m]-mx); esm[m] = e; lsum += e; }
  red[tid] = lsum; __syncthreads();
  for (int st=128; st>0; st>>=1){ if (tid<st) red[tid]+=red[tid+st]; __syncthreads(); }
  const float den = red[0];
  __syncthreads();

  if (tid < 240){
    const int c = tid/40, d = tid%40;
    float acc = 0.f;
    const int m0 = c*150;
    for (int m=m0; m<m0+150; ++m) acc += esm[m]*v_g[(b*LSEQ+m)*40+d];
    part[c][d] = acc;
  }
  __syncthreads();
  if (tid < 40){
    float xv = 0.f;
    #pragma unroll
    for (int c=0;c<6;++c) xv += part[c][tid];
    xr[tid] = xv/den + ztr[tid];
  }
  __syncthreads();
  if (tid < 30){
    const int hd = tid/10, j = tid%10;
    const float* w1 = hd==0?flw1:(hd==1?stw1:edw1);
    const float* b1 = hd==0?flb1:(hd==1?stb1:edb1);
    float a = b1[j];
    #pragma unroll 8
    for (int d=0; d<40; ++d) a += w1[j*40+d]*xr[d];
    hb[tid] = eluf(a);
  }
  __syncthreads();
  if (tid < 3){
    const float* w2 = tid==0?flw2:(tid==1?stw2:edw2);
    const float* b2 = tid==0?flb2:(tid==1?stb2:edb2);
    float a = b2[0];
    #pragma unroll
    for (int j=0;j<10;++j) a += w2[j]*hb[tid*10+j];
    out[tid*NWIN + blk] = a;
  }
}

extern "C" void kernel_launch(void* const* d_in, const int* in_sizes, int n_in,
                              void* d_out, int out_size, void* d_ws, size_t ws_size,
                              hipStream_t stream) {
  const float* z    = (const float*)d_in[0];
  const float* toh  = (const float*)d_in[1];
  const int*   dur  = (const int*)d_in[2];
  const float* cw1  = (const float*)d_in[3];
  const float* cb1  = (const float*)d_in[4];
  const float* cw2  = (const float*)d_in[5];
  const float* cb2  = (const float*)d_in[6];
  const float* cw3  = (const float*)d_in[7];
  const float* cb3  = (const float*)d_in[8];
  const float* cw4  = (const float*)d_in[9];
  const float* cb4  = (const float*)d_in[10];
  const float* fc1w = (const float*)d_in[11];
  const float* fc1b = (const float*)d_in[12];
  const float* fc2w = (const float*)d_in[13];
  const float* fc2b = (const float*)d_in[14];
  const float* embw = (const float*)d_in[15];
  const float* embb = (const float*)d_in[16];
  const float* wq   = (const float*)d_in[17];
  const float* bq   = (const float*)d_in[18];
  const float* wk   = (const float*)d_in[19];
  const float* bk   = (const float*)d_in[20];
  const float* wv   = (const float*)d_in[21];
  const float* bv   = (const float*)d_in[22];
  const float* flw1 = (const float*)d_in[23];
  const float* flb1 = (const float*)d_in[24];
  const float* flw2 = (const float*)d_in[25];
  const float* flb2 = (const float*)d_in[26];
  const float* stw1 = (const float*)d_in[27];
  const float* stb1 = (const float*)d_in[28];
  const float* stw2 = (const float*)d_in[29];
  const float* stb2 = (const float*)d_in[30];
  const float* edw1 = (const float*)d_in[31];
  const float* edb1 = (const float*)d_in[32];
  const float* edw2 = (const float*)d_in[33];
  const float* edb2 = (const float*)d_in[34];

  f16*   wsF = (f16*)d_ws;
  float* wsf = (float*)d_ws;
  float* zt = wsf + FOFF;
  float* q  = wsf + FOFF + 144000;
  float* k  = wsf + FOFF + 288000;
  float* v  = wsf + FOFF + 432000;

  prep2<<<(WEND+255)/256, 256, 0, stream>>>(cw2, cw3, cw4, fc1w, wsF);
  encoder3<<<NBLK, 256, 0, stream>>>(z, toh, cw1, cb1, cb2, cb3, cb4, wsF,
                                     fc1b, fc2w, fc2b, embw, embb,
                                     wq, bq, wk, bk, wv, bv, zt, q, k, v);
  attn_kernel<<<NWIN, 256, 0, stream>>>(q, k, v, zt, dur,
                                        flw1, flb1, flw2, flb2,
                                        stw1, stb1, stw2, stb2,
                                        edw1, edb1, edw2, edb2,
                                        (float*)d_out);
}